// Round 1
// baseline (169.570 us; speedup 1.0000x reference)
//
#include <hip/hip_runtime.h>

// RetrosynthesisAttention: additive (Bahdanau) attention.
//   enc_proj = enc @ W1 + b1   [B,M,U]
//   dec_proj = dec @ W2 + b2   [B,N,U]
//   logits[b,n,m] = sum_u v[u]*tanh(enc_proj[b,m,u]+dec_proj[b,n,u]) + v_b
//   attn = softmax_m(logits);  ctx[b,n,d] = sum_m attn*enc[b,m,d]
// B=16, N=M=D=U=256, all fp32.
//
// Math trick: tanh(x) = 1 - 2/(exp2(K*x)+1), K = 2*log2(e).
// sum_u v_u*tanh(...) = (sum_u v_u) - 2*sum_u v_u*rcp(exp2(K*x)+1).
// The constant sum_u v_u and v_b cancel in softmax -> effective logit = -2*S.
// Projections are stored PRE-SCALED by K; enc_proj stored transposed [B][U][M]
// for coalesced inner-loop loads.

constexpr float KSC   = 2.8853900817779268f;  // 2*log2(e)
constexpr float LOG2E = 1.4426950408889634f;

// ---------------- Kernel A: both projection GEMMs (fp32, 64x64 tile, 4x4/thread)
__global__ __launch_bounds__(256) void proj_kernel(
    const float* __restrict__ enc, const float* __restrict__ dec,
    const float* __restrict__ W1,  const float* __restrict__ b1,
    const float* __restrict__ W2,  const float* __restrict__ b2,
    float* __restrict__ encT,      // [B][U][M], scaled by KSC
    float* __restrict__ decS)      // [B][N][U], scaled by KSC
{
    __shared__ float Xs[32][68];   // [d][m], +4 pad keeps 16B align & spreads banks
    __shared__ float Ws[32][68];   // [d][u]

    const int tid = threadIdx.x;
    const int tm = tid & 15, tu = tid >> 4;
    const int u0   = blockIdx.x * 64;       // 0..3  -> u block
    const int row0 = blockIdx.y * 64;       // 0..127 -> flat row block (enc then dec)
    const bool is_enc = row0 < 4096;
    const float* X    = is_enc ? enc : dec;
    const float* W    = is_enc ? W1  : W2;
    const float* bias = is_enc ? b1  : b2;
    const int rbase = is_enc ? row0 : row0 - 4096;   // flat row within tensor

    float acc[4][4] = {};
    for (int dk = 0; dk < 256; dk += 32) {
        {   // X[rbase..+63][dk..+31] -> Xs[d][m] (transpose on store)
            const int c = tid & 31, r0 = tid >> 5;
            #pragma unroll
            for (int i = 0; i < 8; ++i) {
                const int r = r0 + (i << 3);
                Xs[c][r] = X[(rbase + r) * 256 + dk + c];
            }
        }
        {   // W[dk..+31][u0..+63] -> Ws[d][u]
            const int cc = tid & 63, rr0 = tid >> 6;
            #pragma unroll
            for (int i = 0; i < 8; ++i) {
                const int rr = rr0 + (i << 2);
                Ws[rr][cc] = W[(dk + rr) * 256 + u0 + cc];
            }
        }
        __syncthreads();
        #pragma unroll
        for (int d = 0; d < 32; ++d) {
            const float4 xv = *(const float4*)&Xs[d][tm << 2];
            const float4 wv = *(const float4*)&Ws[d][tu << 2];
            const float xa[4] = {xv.x, xv.y, xv.z, xv.w};
            const float wa[4] = {wv.x, wv.y, wv.z, wv.w};
            #pragma unroll
            for (int i = 0; i < 4; ++i)
                #pragma unroll
                for (int j = 0; j < 4; ++j)
                    acc[i][j] = fmaf(xa[i], wa[j], acc[i][j]);
        }
        __syncthreads();
    }

    const int b = rbase >> 8;
    if (is_enc) {
        const int m0 = (rbase & 255) + (tm << 2);
        #pragma unroll
        for (int j = 0; j < 4; ++j) {
            const int u = u0 + (tu << 2) + j;
            const float bb = bias[u];
            float4 o;
            o.x = KSC * (acc[0][j] + bb);
            o.y = KSC * (acc[1][j] + bb);
            o.z = KSC * (acc[2][j] + bb);
            o.w = KSC * (acc[3][j] + bb);
            *(float4*)&encT[b * 65536 + u * 256 + m0] = o;
        }
    } else {
        const int n0 = (rbase & 255) + (tm << 2);
        const int u  = u0 + (tu << 2);
        #pragma unroll
        for (int i = 0; i < 4; ++i) {
            float4 o;
            o.x = KSC * (acc[i][0] + bias[u + 0]);
            o.y = KSC * (acc[i][1] + bias[u + 1]);
            o.z = KSC * (acc[i][2] + bias[u + 2]);
            o.w = KSC * (acc[i][3] + bias[u + 3]);
            *(float4*)&decS[b * 65536 + (n0 + i) * 256 + u] = o;
        }
    }
}

// ---------------- Kernel B: fused tanh-logits + softmax + context
// Block = (b, n-tile of 4). 256 threads; thread m owns score column m,
// then thread d owns context dim d.
__global__ __launch_bounds__(256) void attn_kernel(
    const float* __restrict__ enc,   // [B][M][D]
    const float* __restrict__ encT,  // [B][U][M], scaled
    const float* __restrict__ decS,  // [B][N][U], scaled
    const float* __restrict__ vw,    // [U]
    float* __restrict__ out_ctx,     // [B][N][D]
    float* __restrict__ out_attn)    // [B][N][M]
{
    __shared__ float dps[4][256];
    __shared__ float vv[256];
    __shared__ float attn_s[4][256];
    __shared__ float redm[4][4];
    __shared__ float reds[4][4];

    const int tid  = threadIdx.x;
    const int b    = blockIdx.y;
    const int n0   = blockIdx.x * 4;
    const int lane = tid & 63, wv_ = tid >> 6;

    #pragma unroll
    for (int t = 0; t < 4; ++t)
        dps[t][tid] = decS[b * 65536 + (n0 + t) * 256 + tid];
    vv[tid] = vw[tid];
    __syncthreads();

    // ---- S[m] = sum_u v_u * rcp(exp2(ep+dp)+1); effective logit = -2*S
    const int m = tid;
    const float* ept = encT + b * 65536 + m;
    float a0 = 0.f, a1 = 0.f, a2 = 0.f, a3 = 0.f;
    #pragma unroll 4
    for (int u = 0; u < 256; ++u) {
        const float ep = ept[u * 256];
        const float vu = vv[u];
        {
            const float e = __builtin_amdgcn_exp2f(ep + dps[0][u]);
            a0 = fmaf(vu, __builtin_amdgcn_rcpf(e + 1.0f), a0);
        }
        {
            const float e = __builtin_amdgcn_exp2f(ep + dps[1][u]);
            a1 = fmaf(vu, __builtin_amdgcn_rcpf(e + 1.0f), a1);
        }
        {
            const float e = __builtin_amdgcn_exp2f(ep + dps[2][u]);
            a2 = fmaf(vu, __builtin_amdgcn_rcpf(e + 1.0f), a2);
        }
        {
            const float e = __builtin_amdgcn_exp2f(ep + dps[3][u]);
            a3 = fmaf(vu, __builtin_amdgcn_rcpf(e + 1.0f), a3);
        }
    }
    float l[4] = {-2.f * a0, -2.f * a1, -2.f * a2, -2.f * a3};

    // ---- softmax over m (256 threads = 4 waves)
    #pragma unroll
    for (int t = 0; t < 4; ++t) {
        float x = l[t];
        #pragma unroll
        for (int off = 32; off > 0; off >>= 1)
            x = fmaxf(x, __shfl_xor(x, off));
        if (lane == 0) redm[t][wv_] = x;
    }
    __syncthreads();
    float p[4];
    #pragma unroll
    for (int t = 0; t < 4; ++t) {
        const float mx = fmaxf(fmaxf(redm[t][0], redm[t][1]),
                               fmaxf(redm[t][2], redm[t][3]));
        p[t] = __builtin_amdgcn_exp2f((l[t] - mx) * LOG2E);
    }
    #pragma unroll
    for (int t = 0; t < 4; ++t) {
        float x = p[t];
        #pragma unroll
        for (int off = 32; off > 0; off >>= 1)
            x += __shfl_xor(x, off);
        if (lane == 0) reds[t][wv_] = x;
    }
    __syncthreads();
    #pragma unroll
    for (int t = 0; t < 4; ++t) {
        const float s = (reds[t][0] + reds[t][1]) + (reds[t][2] + reds[t][3]);
        const float a = p[t] / s;
        attn_s[t][m] = a;
        out_attn[(b * 256 + n0 + t) * 256 + m] = a;
    }
    __syncthreads();

    // ---- context: ctx[t][d] = sum_m attn[t][m] * enc[b][m][d]
    const int d = tid;
    const float* eb = enc + b * 65536 + d;
    float c0 = 0.f, c1 = 0.f, c2 = 0.f, c3 = 0.f;
    #pragma unroll 4
    for (int mm = 0; mm < 256; ++mm) {
        const float ev = eb[mm * 256];
        c0 = fmaf(attn_s[0][mm], ev, c0);
        c1 = fmaf(attn_s[1][mm], ev, c1);
        c2 = fmaf(attn_s[2][mm], ev, c2);
        c3 = fmaf(attn_s[3][mm], ev, c3);
    }
    out_ctx[(b * 256 + n0 + 0) * 256 + d] = c0;
    out_ctx[(b * 256 + n0 + 1) * 256 + d] = c1;
    out_ctx[(b * 256 + n0 + 2) * 256 + d] = c2;
    out_ctx[(b * 256 + n0 + 3) * 256 + d] = c3;
}

extern "C" void kernel_launch(void* const* d_in, const int* in_sizes, int n_in,
                              void* d_out, int out_size, void* d_ws, size_t ws_size,
                              hipStream_t stream) {
    const float* enc = (const float*)d_in[0];
    const float* dec = (const float*)d_in[1];
    const float* W1  = (const float*)d_in[2];
    const float* b1  = (const float*)d_in[3];
    const float* W2  = (const float*)d_in[4];
    const float* b2  = (const float*)d_in[5];
    const float* vw  = (const float*)d_in[6];
    // d_in[7] (v_b) cancels in softmax — unused.

    float* out_ctx  = (float*)d_out;                  // B*N*D = 1048576 floats
    float* out_attn = (float*)d_out + 16 * 256 * 256; // B*N*M = 1048576 floats

    float* encT = (float*)d_ws;                       // 4 MB
    float* decS = encT + 16 * 256 * 256;              // 4 MB

    proj_kernel<<<dim3(4, 128), 256, 0, stream>>>(enc, dec, W1, b1, W2, b2, encT, decS);
    attn_kernel<<<dim3(64, 16), 256, 0, stream>>>(enc, encT, decS, vw, out_ctx, out_attn);
}